// Round 1
// baseline (417.609 us; speedup 1.0000x reference)
//
#include <hip/hip_runtime.h>
#include <hip/hip_bf16.h>
#include <stdint.h>

// ---------------------------------------------------------------------------
// VarianceAdaptor: 3 predictors (conv3x1 -> ReLU -> LN) x2 -> linear, plus
// pitch/energy embedding add and length regulation.
//
// B=32 T=1024 H=F=256 K=3 M=4096 NB=256
//
// GEMM view of conv1d(k=3,pad=1,NWC,WIO): row (b,t) of im2col A is the 768
// contiguous bf16 at &X[b][t-1][0] (zeros page at sequence edges).
// MFMA 16x16x32 bf16; block tile 64 rows x 256 cols (4 waves x 64x64) so the
// block owns complete LayerNorm rows. Epilogues fuse bias+ReLU+LN (+ final
// linear for conv2 -> predictions directly, h2 never materialized).
//
// Scratch: xb (bf16 x), h1b[3] (bf16 conv1 out), wT (bf16 transposed weights)
// live inside the d_out "out" chunk (written last by k_lr). ws holds only
// cum / packed emb indices / zeros page (~260 KB).
// ---------------------------------------------------------------------------

typedef __bf16 bf16;
typedef __attribute__((ext_vector_type(8))) __bf16 bf16x8;
typedef __attribute__((ext_vector_type(4))) float f32x4;

#define TSEQ 1024
#define NROWS 32768          // B*T
#define NCH 24               // 768/32 K-chunks

// output chunk offsets (floats)
#define O1 33554432          // pitch_pred
#define O2 33587200          // energy_pred
#define O3 33619968          // log_dur
#define O4 33652736          // duration passthrough
#define O5 33685504          // mel_len
#define O6 33685536          // mel_mask

// scratch byte offsets inside d_out
#define XB_OFF 0
#define H1B_OFF 16777216
#define H1B_SZ 16777216
#define WT_OFF 67108864
#define WT_SZ 393216         // one 256x768 bf16 matrix

// ws byte offsets
#define CUM_OFF 0
#define ADDROW_OFF 131072
#define ZEROS_OFF 262144

// ---------------------------------------------------------------------------
// fp32 -> swizzled bf16 copy of x.  16B units within each 64B block are
// XOR-permuted by (row&3) so MFMA fragment ds_read_b128 drops to 4-way
// conflicts (global_load_lds forbids padding).
__global__ __launch_bounds__(256) void k_cvt_x(const float* __restrict__ x,
                                               bf16* __restrict__ xb) {
  int t = blockIdx.x * 256 + threadIdx.x;   // 1,048,576 threads
  int g = t >> 5;                           // row 0..32767
  int u = t & 31;                           // 16B unit within row
  const float4* s = (const float4*)(x + ((size_t)g << 8) + (u << 3));
  float4 a = s[0], b = s[1];
  bf16x8 o;
  o[0] = (bf16)a.x; o[1] = (bf16)a.y; o[2] = (bf16)a.z; o[3] = (bf16)a.w;
  o[4] = (bf16)b.x; o[5] = (bf16)b.y; o[6] = (bf16)b.z; o[7] = (bf16)b.w;
  int pos = (u & ~3) | ((u & 3) ^ (g & 3));
  *(bf16x8*)(xb + ((size_t)g << 8) + (pos << 3)) = o;
}

// (3,K,H,F) WIO fp32 -> wT[m][f][k] bf16 (k = dt*256+c), same unit swizzle by f.
// grid (4, 24, 6): f = bx*64 + (tid&63), u = by*4 + (tid>>6), m = bz.
__global__ __launch_bounds__(256) void k_cvt_w(const float* __restrict__ w1,
                                               const float* __restrict__ w2,
                                               bf16* __restrict__ wt) {
  int f = blockIdx.x * 64 + (threadIdx.x & 63);
  int u = blockIdx.y * 4 + (threadIdx.x >> 6);   // 0..95 (16B unit along k)
  int m = blockIdx.z;                            // 0..5
  const float* W = (m < 3) ? w1 : w2;
  int i = (m < 3) ? m : m - 3;
  int dt = u >> 5;
  int c0 = (u & 31) << 3;
  const float* src = W + (((size_t)(i * 3 + dt) * 256 + c0) << 8) + f;
  bf16x8 o;
#pragma unroll
  for (int cc = 0; cc < 8; ++cc) o[cc] = (bf16)src[(size_t)cc << 8];
  int pos = (u & ~3) | ((u & 3) ^ (f & 3));
  *(bf16x8*)(wt + (size_t)m * 196608 + (size_t)f * 768 + (pos << 3)) = o;
}

// cumsum(dur) per batch + mel_len + duration passthrough.
__global__ __launch_bounds__(256) void k_scan(const int* __restrict__ dur,
                                              const int* __restrict__ maxlen,
                                              float* __restrict__ out,
                                              int* __restrict__ cum) {
  int b = blockIdx.x, tid = threadIdx.x;
  __shared__ int lds[256];
  int4 d = ((const int4*)(dur + b * 1024))[tid];
  int p0 = d.x, p1 = p0 + d.y, p2 = p1 + d.z, p3 = p2 + d.w;
  int val = p3;
  lds[tid] = val;
  __syncthreads();
  for (int off = 1; off < 256; off <<= 1) {
    int t = (tid >= off) ? lds[tid - off] : 0;
    __syncthreads();
    val += t;
    lds[tid] = val;
    __syncthreads();
  }
  int excl = val - p3;
  int4 c;
  c.x = excl + p0; c.y = excl + p1; c.z = excl + p2; c.w = excl + p3;
  ((int4*)(cum + b * 1024))[tid] = c;
  float4 fd;
  fd.x = (float)d.x; fd.y = (float)d.y; fd.z = (float)d.z; fd.w = (float)d.w;
  ((float4*)(out + O4 + b * 1024))[tid] = fd;
  if (tid == 255) {
    int mel = val < maxlen[0] ? val : maxlen[0];
    out[O5 + b] = (float)mel;
  }
}

// searchsorted(left) of pitch/energy targets into bins; pack indices.
// Also zeroes the zeros-page (ws is 0xAA-poisoned every launch).
__global__ __launch_bounds__(256) void k_bins(const float* __restrict__ pt,
                                              const float* __restrict__ et,
                                              const float* __restrict__ pbins,
                                              const float* __restrict__ ebins,
                                              int* __restrict__ addrow,
                                              float* __restrict__ zeros) {
  __shared__ float pb[255], eb[255];
  int tid = threadIdx.x;
  if (tid < 255) { pb[tid] = pbins[tid]; eb[tid] = ebins[tid]; }
  if (blockIdx.x == 0 && tid < 64) zeros[tid] = 0.f;
  __syncthreads();
  int g = blockIdx.x * 256 + tid;
  float pv = pt[g], ev = et[g];
  int lo = 0, hi = 255;
  while (lo < hi) { int md = (lo + hi) >> 1; if (pb[md] < pv) lo = md + 1; else hi = md; }
  int pi = lo;
  lo = 0; hi = 255;
  while (lo < hi) { int md = (lo + hi) >> 1; if (eb[md] < ev) lo = md + 1; else hi = md; }
  addrow[g] = pi | (lo << 16);
}

// ---------------------------------------------------------------------------
// Fused conv(k=3) GEMM + bias + ReLU + LayerNorm (+ linear head for mode=1).
// grid (512, 3): x = 64-row tile, y = predictor. 256 threads = 4 waves, each
// wave computes 64 rows x 64 cols via 4x4 MFMA 16x16x32 bf16 tiles.
__global__ __launch_bounds__(256) void k_conv(
    const char* __restrict__ Ab, size_t AperY, const char* __restrict__ Wb,
    const float* __restrict__ bias0, const float* __restrict__ gamma0,
    const float* __restrict__ beta0, char* __restrict__ hout0,
    const float* __restrict__ lw0, const float* __restrict__ lb0,
    const unsigned char* __restrict__ mask, float* __restrict__ outb,
    const char* __restrict__ zeros, int mode) {
  __shared__ __align__(16) char Asm[64 * 64];    // 64 rows x 32 bf16
  __shared__ __align__(16) char Bsm[256 * 64];   // 256 f-rows x 32 bf16
  __shared__ float redS[64][4];
  __shared__ float redS2[64][4];
  __shared__ float predr[64][4];

  int tid = threadIdx.x;
  int wv = tid >> 6;
  int ln = tid & 63;
  int q = ln >> 4;
  int m16 = ln & 15;
  int y = blockIdx.y;
  int g0 = blockIdx.x << 6;
  int t0 = g0 & (TSEQ - 1);

  const char* A = Ab + (size_t)y * AperY;
  const char* W = Wb + (size_t)y * WT_SZ;
  const float* bias = bias0 + y * 256;
  const float* gamma = gamma0 + y * 256;
  const float* beta = beta0 + y * 256;

  int rA = (wv << 4) + (ln >> 2);   // A row this lane stages
  int slot = ln & 3;
  char* ldsA = Asm + (tid << 4);

  f32x4 acc[4][4];
#pragma unroll
  for (int a = 0; a < 4; a++)
#pragma unroll
    for (int b = 0; b < 4; b++) acc[a][b] = (f32x4){0.f, 0.f, 0.f, 0.f};

  for (int kb = 0; kb < NCH; ++kb) {
    int dt0 = kb >> 3;
    int c0 = (kb & 7) << 5;
    {
      int u = t0 + rA + dt0 - 1;
      const char* src;
      if ((unsigned)u < TSEQ)
        src = A + (((size_t)(g0 + rA + dt0 - 1) << 8) + c0 + (slot << 3)) * 2;
      else
        src = zeros + (slot << 4);
      __builtin_amdgcn_global_load_lds(
          (const __attribute__((address_space(1))) void*)src,
          (__attribute__((address_space(3))) void*)ldsA, 16, 0, 0);
    }
#pragma unroll
    for (int ii = 0; ii < 4; ++ii) {
      int f = (wv << 6) + (ii << 4) + (ln >> 2);
      const char* src = W + ((size_t)f * 768 + (kb << 5) + (slot << 3)) * 2;
      char* dst = Bsm + (wv << 12) + (ii << 10) + (ln << 4);
      __builtin_amdgcn_global_load_lds(
          (const __attribute__((address_space(1))) void*)src,
          (__attribute__((address_space(3))) void*)dst, 16, 0, 0);
    }
    __syncthreads();

    int swA = ((g0 + m16 + dt0 + 3) & 3) ^ q;   // row-swizzle of xb/h1b
    int swB = q ^ (m16 & 3);                    // row-swizzle of wT
    bf16x8 af[4], bfr[4];
#pragma unroll
    for (int mi = 0; mi < 4; mi++)
      af[mi] = *(const bf16x8*)(Asm + (((mi << 4) + m16) << 6) + (swA << 4));
#pragma unroll
    for (int ni = 0; ni < 4; ni++)
      bfr[ni] = *(const bf16x8*)(Bsm + (((wv << 6) + (ni << 4) + m16) << 6) + (swB << 4));
#pragma unroll
    for (int mi = 0; mi < 4; mi++)
#pragma unroll
      for (int ni = 0; ni < 4; ni++)
        acc[mi][ni] = __builtin_amdgcn_mfma_f32_16x16x32_bf16(af[mi], bfr[ni],
                                                              acc[mi][ni], 0, 0, 0);
    __syncthreads();
  }

  // bias + ReLU + LN stats (cross-wave via LDS partials)
  float bias_v[4], g_v[4], be_v[4], lw_v[4];
#pragma unroll
  for (int ni = 0; ni < 4; ni++) {
    int nf = (wv << 6) + (ni << 4) + m16;
    bias_v[ni] = bias[nf];
    g_v[ni] = gamma[nf];
    be_v[ni] = beta[nf];
  }
  if (mode) {
    const float* lw = lw0 + y * 256;
#pragma unroll
    for (int ni = 0; ni < 4; ni++) lw_v[ni] = lw[(wv << 6) + (ni << 4) + m16];
  }

#pragma unroll
  for (int mi = 0; mi < 4; mi++) {
#pragma unroll
    for (int r = 0; r < 4; r++) {
      float s1 = 0.f, s2 = 0.f;
#pragma unroll
      for (int ni = 0; ni < 4; ni++) {
        float v = acc[mi][ni][r] + bias_v[ni];
        v = fmaxf(v, 0.f);
        acc[mi][ni][r] = v;
        s1 += v;
        s2 += v * v;
      }
#pragma unroll
      for (int d = 1; d < 16; d <<= 1) {
        s1 += __shfl_xor(s1, d);
        s2 += __shfl_xor(s2, d);
      }
      if (m16 == 0) {
        int m = (mi << 4) + (q << 2) + r;
        redS[m][wv] = s1;
        redS2[m][wv] = s2;
      }
    }
  }
  __syncthreads();

  if (mode == 0) {
    bf16* hp = (bf16*)(hout0 + (size_t)y * H1B_SZ);
#pragma unroll
    for (int mi = 0; mi < 4; mi++) {
#pragma unroll
      for (int r = 0; r < 4; r++) {
        int m = (mi << 4) + (q << 2) + r;
        float mu = (redS[m][0] + redS[m][1] + redS[m][2] + redS[m][3]) * 0.00390625f;
        float var = (redS2[m][0] + redS2[m][1] + redS2[m][2] + redS2[m][3]) * 0.00390625f - mu * mu;
        float rs = rsqrtf(var + 1e-5f);
        int gg = g0 + m;
#pragma unroll
        for (int ni = 0; ni < 4; ni++) {
          float v = (acc[mi][ni][r] - mu) * rs * g_v[ni] + be_v[ni];
          int n = (wv << 6) + (ni << 4) + m16;
          int pos = (n & ~31) | ((((n >> 3) & 3) ^ (gg & 3)) << 3) | (n & 7);
          hp[((size_t)gg << 8) + pos] = (bf16)v;   // swizzled: conv2's A input
        }
      }
    }
  } else {
#pragma unroll
    for (int mi = 0; mi < 4; mi++) {
#pragma unroll
      for (int r = 0; r < 4; r++) {
        int m = (mi << 4) + (q << 2) + r;
        float mu = (redS[m][0] + redS[m][1] + redS[m][2] + redS[m][3]) * 0.00390625f;
        float var = (redS2[m][0] + redS2[m][1] + redS2[m][2] + redS2[m][3]) * 0.00390625f - mu * mu;
        float rs = rsqrtf(var + 1e-5f);
        float p = 0.f;
#pragma unroll
        for (int ni = 0; ni < 4; ni++) {
          float v = (acc[mi][ni][r] - mu) * rs * g_v[ni] + be_v[ni];
          p += v * lw_v[ni];
        }
#pragma unroll
        for (int d = 1; d < 16; d <<= 1) p += __shfl_xor(p, d);
        if (m16 == 0) predr[m][wv] = p;
      }
    }
    __syncthreads();
    if (tid < 64) {
      int gg = g0 + tid;
      float p = predr[tid][0] + predr[tid][1] + predr[tid][2] + predr[tid][3] + lb0[y];
      if (mask[gg]) p = 0.f;
      float* pd = outb + (y == 0 ? O3 : (y == 1 ? O1 : O2));
      pd[gg] = p;
    }
  }
}

// Length regulation: out[b,j,:] = x[b,i,:] + pitch_emb[pi,:] + energy_emb[ei,:]
// with i = upper_bound(cum[b], j), zeroed past mel_len. One wave per out row.
__global__ __launch_bounds__(256) void k_lr(const float* __restrict__ x,
                                            const int* __restrict__ cum,
                                            const int* __restrict__ addrow,
                                            const float* __restrict__ pemb,
                                            const float* __restrict__ eemb,
                                            const int* __restrict__ maxlen,
                                            float* __restrict__ outb) {
  int rid = blockIdx.x * 4 + (threadIdx.x >> 6);
  int lane = threadIdx.x & 63;
  int b = rid >> 12;
  int j = rid & 4095;
  const int* cb = cum + (b << 10);
  int total = cb[1023];
  int mel = total < maxlen[0] ? total : maxlen[0];
  bool valid = j < mel;
  float4 res = {0.f, 0.f, 0.f, 0.f};
  if (valid) {
    int lo = 0, hi = 1024;
    while (lo < hi) { int md = (lo + hi) >> 1; if (cb[md] <= j) lo = md + 1; else hi = md; }
    int i = lo < 1023 ? lo : 1023;
    int ar = addrow[(b << 10) + i];
    int pi = ar & 0xffff, ei = ar >> 16;
    const float4* xr = (const float4*)(x + (((size_t)(b << 10) + i) << 8));
    const float4* pr = (const float4*)(pemb + ((size_t)pi << 8));
    const float4* er = (const float4*)(eemb + ((size_t)ei << 8));
    float4 a = xr[lane], p = pr[lane], e = er[lane];
    res.x = a.x + p.x + e.x;
    res.y = a.y + p.y + e.y;
    res.z = a.z + p.z + e.z;
    res.w = a.w + p.w + e.w;
  }
  ((float4*)(outb + ((size_t)rid << 8)))[lane] = res;
  if (lane == 0) outb[O6 + rid] = valid ? 0.f : 1.f;
}

// ---------------------------------------------------------------------------
extern "C" void kernel_launch(void* const* d_in, const int* in_sizes, int n_in,
                              void* d_out, int out_size, void* d_ws, size_t ws_size,
                              hipStream_t stream) {
  const float* x = (const float*)d_in[0];
  const unsigned char* src_mask = (const unsigned char*)d_in[1];
  const int* dur = (const int*)d_in[2];
  const float* pt = (const float*)d_in[3];
  const float* et = (const float*)d_in[4];
  const int* maxlen = (const int*)d_in[5];
  const float* w1 = (const float*)d_in[6];
  const float* b1 = (const float*)d_in[7];
  const float* g1 = (const float*)d_in[8];
  const float* be1 = (const float*)d_in[9];
  const float* w2 = (const float*)d_in[10];
  const float* b2 = (const float*)d_in[11];
  const float* g2 = (const float*)d_in[12];
  const float* be2 = (const float*)d_in[13];
  const float* lw = (const float*)d_in[14];
  const float* lb = (const float*)d_in[15];
  const float* pbins = (const float*)d_in[16];
  const float* pemb = (const float*)d_in[17];
  const float* ebins = (const float*)d_in[18];
  const float* eemb = (const float*)d_in[19];

  float* outf = (float*)d_out;
  char* ob = (char*)d_out;
  bf16* xb = (bf16*)(ob + XB_OFF);
  char* h1b = ob + H1B_OFF;
  bf16* wt = (bf16*)(ob + WT_OFF);
  int* cum = (int*)((char*)d_ws + CUM_OFF);
  int* addrow = (int*)((char*)d_ws + ADDROW_OFF);
  float* zeros = (float*)((char*)d_ws + ZEROS_OFF);

  hipLaunchKernelGGL(k_cvt_x, dim3(4096), dim3(256), 0, stream, x, xb);
  hipLaunchKernelGGL(k_cvt_w, dim3(4, 24, 6), dim3(256), 0, stream, w1, w2, wt);
  hipLaunchKernelGGL(k_bins, dim3(128), dim3(256), 0, stream, pt, et, pbins, ebins,
                     addrow, zeros);
  hipLaunchKernelGGL(k_scan, dim3(32), dim3(256), 0, stream, dur, maxlen, outf, cum);
  hipLaunchKernelGGL(k_conv, dim3(512, 3), dim3(256), 0, stream,
                     (const char*)xb, (size_t)0, (const char*)wt, b1, g1, be1, h1b,
                     lw, lb, src_mask, outf, (const char*)zeros, 0);
  hipLaunchKernelGGL(k_conv, dim3(512, 3), dim3(256), 0, stream,
                     (const char*)h1b, (size_t)H1B_SZ,
                     (const char*)(ob + WT_OFF + 3 * WT_SZ), b2, g2, be2,
                     (char*)nullptr, lw, lb, src_mask, outf, (const char*)zeros, 1);
  hipLaunchKernelGGL(k_lr, dim3(32768), dim3(256), 0, stream, x, cum, addrow, pemb,
                     eemb, maxlen, outf);
}